// Round 5
// baseline (899.785 us; speedup 1.0000x reference)
//
#include <hip/hip_runtime.h>
#include <stdint.h>

static constexpr int NT = 26000;   // n_terms
static constexpr int NE = 120000;  // n_edges

typedef __attribute__((ext_vector_type(8))) short short8;   // 8 bf16 (MFMA A/B frag)
typedef __attribute__((ext_vector_type(4))) float f32x4;    // MFMA C/D frag

// ---------- bf16 helpers ----------
__device__ __forceinline__ float bf_lo(uint32_t u){ union{uint32_t u; float f;} a; a.u = u<<16; return a.f; }
__device__ __forceinline__ float bf_hi(uint32_t u){ union{uint32_t u; float f;} a; a.u = u & 0xffff0000u; return a.f; }
__device__ __forceinline__ uint32_t f2b(float f){ union{float f; uint32_t u;} a; a.f=f; return (a.u + 0x7fffu + ((a.u>>16)&1u))>>16; }

// ---------- CSR build ----------
__global__ __launch_bounds__(256) void k_zero_deg(int* __restrict__ deg){
  int i = blockIdx.x*256 + threadIdx.x;
  if (i < NT) deg[i] = 0;
}
__global__ __launch_bounds__(256) void k_count(const int* __restrict__ ei, int* __restrict__ deg){
  int e = blockIdx.x*256 + threadIdx.x;
  if (e < NE) atomicAdd(&deg[ei[e]], 1);
}
// slots = max(4, ceil4(deg)); rp = prefix(slots); cur = rp (fill advances cur to rp+deg)
__global__ __launch_bounds__(1024) void k_scan(const int* __restrict__ deg, int* __restrict__ rp,
                                               int* __restrict__ cur){
  __shared__ int part[1024];
  const int t = threadIdx.x;
  const int CH = (NT + 1023)/1024;   // 26
  const int base = t*CH;
  int sum = 0;
  for (int i=0;i<CH;i++){
    int idx=base+i;
    if (idx<NT){ int d = deg[idx]; sum += (d<=4)?4:((d+3)&~3); }
  }
  part[t] = sum;
  __syncthreads();
  for (int off=1; off<1024; off<<=1){
    int v = (t>=off) ? part[t-off] : 0;
    __syncthreads();
    part[t] += v;
    __syncthreads();
  }
  int run = (t==0) ? 0 : part[t-1];
  for (int i=0;i<CH;i++){
    int idx = base+i;
    if (idx<NT){
      int d = deg[idx];
      int slot = (d<=4)?4:((d+3)&~3);
      rp[idx] = run; cur[idx] = run;
      run += slot;
    }
  }
  if (t==1023) rp[NT] = part[1023];
}
// init: zero the 4KB zero-page; fill cols16 (224008 u16) with NT (0x6590)
__global__ __launch_bounds__(256) void k_init(uint32_t* __restrict__ zp, uint32_t* __restrict__ cols32){
  int i = blockIdx.x*256 + threadIdx.x;
  if (i < 1024) zp[i] = 0;
  else if (i < 1024 + 112004) cols32[i-1024] = 0x65906590u;  // 26000 | 26000<<16
}
__global__ __launch_bounds__(256) void k_fill(const int* __restrict__ ei, int* __restrict__ cur,
                                              uint16_t* __restrict__ cols){
  int e = blockIdx.x*256 + threadIdx.x;
  if (e < NE){
    int r = ei[e];
    int pos = atomicAdd(&cur[r], 1);
    cols[pos] = (uint16_t)ei[NE + e];
  }
}
// pre-pack weights to bf16 [COUT][CIN], zero-padded K
__global__ __launch_bounds__(256) void k_prepw(const float* __restrict__ W1, const float* __restrict__ W2,
                                               const float* __restrict__ W3,
                                               uint16_t* __restrict__ Wt1, uint16_t* __restrict__ Wt2,
                                               uint16_t* __restrict__ Wt3){
  for (int idx = threadIdx.x; idx < 8192; idx += 256){
    if (idx < 2048){           // W1: 64 x 22 -> [64][32]
      int o = idx >> 5, k = idx & 31;
      Wt1[idx] = (uint16_t)((k < 22) ? f2b(W1[o*22 + k]) : 0);
    } else if (idx < 6144){    // W2: 64 x 64
      int j = idx - 2048;
      Wt2[j] = (uint16_t)f2b(W2[j]);
    } else {                   // W3: 32 x 64
      int j = idx - 6144;
      Wt3[j] = (uint16_t)f2b(W3[j]);
    }
  }
}

// ---------- build h0: [N][32][32] bf16, features = [x(14), emb(8), zeros(10)] ----------
__global__ __launch_bounds__(256) void k_build_h0(const float* __restrict__ x, const int* __restrict__ tidx,
                                                  const float* __restrict__ emb, uint32_t* __restrict__ h0){
  int n = blockIdx.x*8 + (threadIdx.x>>5);
  int b = threadIdx.x & 31;
  const float* xr = x + ((size_t)b*NT + n)*14;
  const float* er = emb + (size_t)tidx[n]*8;
  float v[32];
  #pragma unroll
  for (int i=0;i<14;i++) v[i]=xr[i];
  #pragma unroll
  for (int i=0;i<8;i++) v[14+i]=er[i];
  #pragma unroll
  for (int i=22;i<32;i++) v[i]=0.f;
  uint32_t* dst = h0 + ((size_t)n*32 + b)*16;
  #pragma unroll
  for (int u=0;u<16;u++) dst[u] = f2b(v[2*u]) | (f2b(v[2*u+1])<<16);
}

// ---------- gather helpers ----------
template<int STR>   // STR = u32 per node block = 16*CIN
__device__ __forceinline__ const uint32_t* nb(const uint32_t* __restrict__ hin,
                                              const uint32_t* __restrict__ zp, int c){
  return (c < NT) ? (hin + (size_t)c*STR) : zp;   // scalar select (c wave-uniform)
}
template<int KS>
__device__ __forceinline__ void gloadv(uint4 (&v)[KS], const uint32_t* __restrict__ p, uint32_t off){
  #pragma unroll
  for (int ks=0; ks<KS; ks++) v[ks] = *reinterpret_cast<const uint4*>(p + off + ks*16);
}
template<int KS>
__device__ __forceinline__ void accum(float (&acc)[KS][8], const uint4 (&v)[KS]){
  #pragma unroll
  for (int ks=0;ks<KS;ks++){
    acc[ks][0]+=bf_lo(v[ks].x); acc[ks][1]+=bf_hi(v[ks].x);
    acc[ks][2]+=bf_lo(v[ks].y); acc[ks][3]+=bf_hi(v[ks].y);
    acc[ks][4]+=bf_lo(v[ks].z); acc[ks][5]+=bf_hi(v[ks].z);
    acc[ks][6]+=bf_lo(v[ks].w); acc[ks][7]+=bf_hi(v[ks].w);
  }
}

// ---------- fused layer: 2 waves per node (batch-rows 0-15 / 16-31); no LDS, no barriers;
// branch-free depth-4 edge pipeline over padded CSR; zero-page absorbs pads/overrun prefetch.
// D = W * s^T via mfma_f32_16x16x32_bf16; D col(lane&15)=batch row, row((lane>>4)*4+reg)=out ch.
template<int CIN, int COUT, bool FINAL, int MINW>
__global__ __launch_bounds__(256, MINW) void k_layer(
    const uint32_t* __restrict__ hin,   // [NT][32][CIN] bf16
    uint32_t* __restrict__ hout,        // [NT][32][COUT] bf16 (unused if FINAL)
    const int* __restrict__ rp, const int* __restrict__ cur,
    const uint16_t* __restrict__ cols, const uint32_t* __restrict__ zp,
    const uint16_t* __restrict__ Wt,    // [COUT][CIN] bf16 pre-packed
    const float* __restrict__ bias,
    const float* __restrict__ Wo, const float* __restrict__ bo,
    float* __restrict__ out)            // [32][NT] f32, pre-offset by chunk
{
  constexpr int KS  = CIN/32;
  constexpr int OT  = COUT/16;
  constexpr int STR = 16*CIN;

  const int t    = threadIdx.x;
  const int lane = t & 63;
  const int w    = t >> 6;
  const int l15  = lane & 15;
  const int lg   = lane >> 4;
  const int rt   = w & 1;
  const int node = blockIdx.x*2 + (w>>1);

  const uint32_t off = (uint32_t)((rt*16 + l15)*(CIN/2) + lg*4);

  const int e0 = __builtin_amdgcn_readfirstlane(rp[node]);
  const int e1 = __builtin_amdgcn_readfirstlane(rp[node+1]);
  const int dg = __builtin_amdgcn_readfirstlane(cur[node]) - e0;

  // prologue: first 4 targets + own block, all in flight together
  uint2 cc0 = *reinterpret_cast<const uint2*>(cols + e0);
  int q0 = __builtin_amdgcn_readfirstlane(cc0.x);
  int q1 = __builtin_amdgcn_readfirstlane(cc0.y);
  uint4 v0[KS], v1[KS], v2[KS], v3[KS], own[KS];
  gloadv<KS>(v0, nb<STR>(hin, zp, q0 & 0xffff), off);
  gloadv<KS>(v1, nb<STR>(hin, zp, (q0 >> 16) & 0xffff), off);
  gloadv<KS>(v2, nb<STR>(hin, zp, q1 & 0xffff), off);
  gloadv<KS>(v3, nb<STR>(hin, zp, (q1 >> 16) & 0xffff), off);
  gloadv<KS>(own, hin + (size_t)node*STR, off);
  uint2 ccA = *reinterpret_cast<const uint2*>(cols + e0 + 4);

  const float degf = (float)(dg > 1 ? dg : 1);
  float acc[KS][8];
  #pragma unroll
  for (int ks=0;ks<KS;ks++){
    acc[ks][0]=bf_lo(own[ks].x)*degf; acc[ks][1]=bf_hi(own[ks].x)*degf;
    acc[ks][2]=bf_lo(own[ks].y)*degf; acc[ks][3]=bf_hi(own[ks].y)*degf;
    acc[ks][4]=bf_lo(own[ks].z)*degf; acc[ks][5]=bf_hi(own[ks].z)*degf;
    acc[ks][6]=bf_lo(own[ks].w)*degf; acc[ks][7]=bf_hi(own[ks].w)*degf;
  }

  // branch-free depth-4 pipeline; trailing prefetches clamp to zero-page (L1-hot)
  for (int e = e0; e < e1; e += 4){
    uint2 ccN = *reinterpret_cast<const uint2*>(cols + e + 8);   // 8 sentinels at array end
    int p0 = __builtin_amdgcn_readfirstlane(ccA.x);
    int p1 = __builtin_amdgcn_readfirstlane(ccA.y);
    int n0 = (e+4 < e1) ? (p0 & 0xffff)         : NT;
    int n1 = (e+5 < e1) ? ((p0 >> 16) & 0xffff) : NT;
    int n2 = (e+6 < e1) ? (p1 & 0xffff)         : NT;
    int n3 = (e+7 < e1) ? ((p1 >> 16) & 0xffff) : NT;
    accum<KS>(acc, v0); gloadv<KS>(v0, nb<STR>(hin, zp, n0), off);
    accum<KS>(acc, v1); gloadv<KS>(v1, nb<STR>(hin, zp, n1), off);
    accum<KS>(acc, v2); gloadv<KS>(v2, nb<STR>(hin, zp, n2), off);
    accum<KS>(acc, v3); gloadv<KS>(v3, nb<STR>(hin, zp, n3), off);
    ccA = ccN;
  }

  // s = acc/deg -> bf16 B-frag (this wave's 16 batch rows)
  const float di = 1.0f / degf;
  short8 bfrag[KS];
  #pragma unroll
  for (int ks=0;ks<KS;ks++){
    short8 bf;
    #pragma unroll
    for (int j=0;j<8;j++) bf[j] = (short)f2b(acc[ks][j]*di);
    bfrag[ks]=bf;
  }

  if constexpr (!FINAL){
    #pragma unroll
    for (int ot=0;ot<OT;ot++){
      const int o0 = ot*16;
      short8 af[KS];
      #pragma unroll
      for (int ks=0;ks<KS;ks++)
        af[ks] = *reinterpret_cast<const short8*>(Wt + (o0 + l15)*CIN + ks*32 + lg*8);
      f32x4 d = *reinterpret_cast<const f32x4*>(bias + o0 + lg*4);   // bias folded into C
      #pragma unroll
      for (int ks=0;ks<KS;ks++)
        d = __builtin_amdgcn_mfma_f32_16x16x32_bf16(af[ks], bfrag[ks], d, 0,0,0);
      const int brow = rt*16 + l15;
      float a0=fmaxf(d[0],0.f), a1=fmaxf(d[1],0.f), a2=fmaxf(d[2],0.f), a3=fmaxf(d[3],0.f);
      uint2 p; p.x = f2b(a0) | (f2b(a1)<<16); p.y = f2b(a2) | (f2b(a3)<<16);
      *reinterpret_cast<uint2*>(hout + (size_t)node*(16*COUT) + brow*(COUT/2) + (o0 + lg*4)/2) = p;
    }
  } else {
    float z = 0.f;
    #pragma unroll
    for (int ot=0;ot<OT;ot++){
      const int o0 = ot*16;
      short8 af[KS];
      #pragma unroll
      for (int ks=0;ks<KS;ks++)
        af[ks] = *reinterpret_cast<const short8*>(Wt + (o0 + l15)*CIN + ks*32 + lg*8);
      f32x4 d = *reinterpret_cast<const f32x4*>(bias + o0 + lg*4);
      #pragma unroll
      for (int ks=0;ks<KS;ks++)
        d = __builtin_amdgcn_mfma_f32_16x16x32_bf16(af[ks], bfrag[ks], d, 0,0,0);
      f32x4 wv = *reinterpret_cast<const f32x4*>(Wo + o0 + lg*4);
      #pragma unroll
      for (int j=0;j<4;j++) z += fmaxf(d[j],0.f)*wv[j];
    }
    z += __shfl_xor(z, 16, 64);
    z += __shfl_xor(z, 32, 64);
    if (lg == 0){
      float sg = 1.f/(1.f + expf(-(z + bo[0])));
      out[(size_t)(rt*16 + l15)*NT + node] = sg;
    }
  }
}

// ---------- workspace layout (bytes); total must stay <= 213,784,016 (proven available) ----------
static constexpr size_t OFF_BUFB = 106496000;                 // bufA: [NT][32][64] bf16 max
static constexpr size_t OFF_ZP   = 212992000;                 // 4 KB zero page
static constexpr size_t OFF_WT1  = OFF_ZP  + 4096;
static constexpr size_t OFF_WT2  = OFF_WT1 + 4096;            // 64*32*2
static constexpr size_t OFF_WT3  = OFF_WT2 + 8192;            // 64*64*2
static constexpr size_t OFF_DEG  = OFF_WT3 + 4096;            // 32*64*2
static constexpr size_t OFF_RP   = OFF_DEG + 104000;
static constexpr size_t OFF_CUR  = OFF_RP  + 104016;
static constexpr size_t OFF_COLS = OFF_CUR + 104000;
static constexpr size_t WS_NEED  = OFF_COLS + 448016;         // 224008 u16 cols (incl 8 sentinels)

extern "C" void kernel_launch(void* const* d_in, const int* in_sizes, int n_in,
                              void* d_out, int out_size, void* d_ws, size_t ws_size,
                              hipStream_t stream)
{
  const float* x    = (const float*)d_in[0];
  const int*   ei   = (const int*)  d_in[1];
  const int*   tidx = (const int*)  d_in[2];
  const float* emb  = (const float*)d_in[3];
  const float* W1   = (const float*)d_in[4];
  const float* b1   = (const float*)d_in[5];
  const float* W2   = (const float*)d_in[6];
  const float* b2   = (const float*)d_in[7];
  const float* W3   = (const float*)d_in[8];
  const float* b3   = (const float*)d_in[9];
  const float* Wo   = (const float*)d_in[10];
  const float* bo   = (const float*)d_in[11];
  float* out = (float*)d_out;

  if (ws_size < WS_NEED) return;

  char* ws = (char*)d_ws;
  uint32_t* bufA  = (uint32_t*)(ws);
  uint32_t* bufB  = (uint32_t*)(ws + OFF_BUFB);
  uint32_t* zp    = (uint32_t*)(ws + OFF_ZP);
  uint16_t* Wt1   = (uint16_t*)(ws + OFF_WT1);
  uint16_t* Wt2   = (uint16_t*)(ws + OFF_WT2);
  uint16_t* Wt3   = (uint16_t*)(ws + OFF_WT3);
  int*      deg   = (int*)     (ws + OFF_DEG);
  int*      rp    = (int*)     (ws + OFF_RP);
  int*      cur   = (int*)     (ws + OFF_CUR);
  uint16_t* cols  = (uint16_t*)(ws + OFF_COLS);

  k_zero_deg<<<(NT+255)/256, 256, 0, stream>>>(deg);
  k_count   <<<(NE+255)/256, 256, 0, stream>>>(ei, deg);
  k_scan    <<<1, 1024, 0, stream>>>(deg, rp, cur);
  k_init    <<<442, 256, 0, stream>>>(zp, (uint32_t*)cols);
  k_fill    <<<(NE+255)/256, 256, 0, stream>>>(ei, cur, cols);
  k_prepw   <<<1, 256, 0, stream>>>(W1, W2, W3, Wt1, Wt2, Wt3);

  for (int ch = 0; ch < 2; ch++){
    k_build_h0<<<NT/8, 256, 0, stream>>>(x + (size_t)ch*32*NT*14, tidx, emb, bufA);
    k_layer<32,64,false,8><<<NT/2, 256, 0, stream>>>(bufA, bufB, rp, cur, cols, zp, Wt1, b1,
                                                     nullptr, nullptr, nullptr);
    k_layer<64,64,false,7><<<NT/2, 256, 0, stream>>>(bufB, bufA, rp, cur, cols, zp, Wt2, b2,
                                                     nullptr, nullptr, nullptr);
    k_layer<64,32,true ,7><<<NT/2, 256, 0, stream>>>(bufA, nullptr, rp, cur, cols, zp, Wt3, b3,
                                                     Wo, bo, out + (size_t)ch*32*NT);
  }
}

// Round 6
// 766.176 us; speedup vs baseline: 1.1744x; 1.1744x over previous
//
#include <hip/hip_runtime.h>
#include <stdint.h>

static constexpr int NT = 26000;   // n_terms
static constexpr int NE = 120000;  // n_edges

typedef __attribute__((ext_vector_type(8))) short short8;   // 8 bf16 (MFMA A/B frag)
typedef __attribute__((ext_vector_type(4))) float f32x4;    // MFMA C/D frag

// ---------- bf16 helpers ----------
__device__ __forceinline__ float bf_lo(uint32_t u){ union{uint32_t u; float f;} a; a.u = u<<16; return a.f; }
__device__ __forceinline__ float bf_hi(uint32_t u){ union{uint32_t u; float f;} a; a.u = u & 0xffff0000u; return a.f; }
__device__ __forceinline__ uint32_t f2b(float f){ union{float f; uint32_t u;} a; a.f=f; return (a.u + 0x7fffu + ((a.u>>16)&1u))>>16; }

// Node-block tiled layout (bf16 element (brow,k) -> u32 offset within block):
//   pos_u32 = (brow>>4)*(CIN*8) + (k>>4)*128 + (brow&15)*8 + (k&15)/2
// i.e. [brow_hi][k_hi] tiles of 16x16 bf16 = 512B. Gathers/stores become contiguous bursts.

// ---------- CSR build ----------
__global__ __launch_bounds__(256) void k_zero_deg(int* __restrict__ deg){
  int i = blockIdx.x*256 + threadIdx.x;
  if (i < NT) deg[i] = 0;
}
__global__ __launch_bounds__(256) void k_count(const int* __restrict__ ei, int* __restrict__ deg){
  int e = blockIdx.x*256 + threadIdx.x;
  if (e < NE) atomicAdd(&deg[ei[e]], 1);
}
// slots = max(4, ceil4(deg)); rp = prefix(slots); cur = rp (fill advances cur to rp+deg)
__global__ __launch_bounds__(1024) void k_scan(const int* __restrict__ deg, int* __restrict__ rp,
                                               int* __restrict__ cur){
  __shared__ int part[1024];
  const int t = threadIdx.x;
  const int CH = (NT + 1023)/1024;   // 26
  const int base = t*CH;
  int sum = 0;
  for (int i=0;i<CH;i++){
    int idx=base+i;
    if (idx<NT){ int d = deg[idx]; sum += (d<=4)?4:((d+3)&~3); }
  }
  part[t] = sum;
  __syncthreads();
  for (int off=1; off<1024; off<<=1){
    int v = (t>=off) ? part[t-off] : 0;
    __syncthreads();
    part[t] += v;
    __syncthreads();
  }
  int run = (t==0) ? 0 : part[t-1];
  for (int i=0;i<CH;i++){
    int idx = base+i;
    if (idx<NT){
      int d = deg[idx];
      int slot = (d<=4)?4:((d+3)&~3);
      rp[idx] = run; cur[idx] = run;
      run += slot;
    }
  }
  if (t==1023) rp[NT] = part[1023];
}
// init: zero the 4KB zero-page; fill cols16 (224008 u16) with NT (0x6590)
__global__ __launch_bounds__(256) void k_init(uint32_t* __restrict__ zp, uint32_t* __restrict__ cols32){
  int i = blockIdx.x*256 + threadIdx.x;
  if (i < 1024) zp[i] = 0;
  else if (i < 1024 + 112004) cols32[i-1024] = 0x65906590u;  // 26000 | 26000<<16
}
__global__ __launch_bounds__(256) void k_fill(const int* __restrict__ ei, int* __restrict__ cur,
                                              uint16_t* __restrict__ cols){
  int e = blockIdx.x*256 + threadIdx.x;
  if (e < NE){
    int r = ei[e];
    int pos = atomicAdd(&cur[r], 1);
    cols[pos] = (uint16_t)ei[NE + e];
  }
}
// pre-pack weights to bf16 [COUT][CIN] row-major, zero-padded K
__global__ __launch_bounds__(256) void k_prepw(const float* __restrict__ W1, const float* __restrict__ W2,
                                               const float* __restrict__ W3,
                                               uint16_t* __restrict__ Wt1, uint16_t* __restrict__ Wt2,
                                               uint16_t* __restrict__ Wt3){
  for (int idx = threadIdx.x; idx < 8192; idx += 256){
    if (idx < 2048){           // W1: 64 x 22 -> [64][32]
      int o = idx >> 5, k = idx & 31;
      Wt1[idx] = (uint16_t)((k < 22) ? f2b(W1[o*22 + k]) : 0);
    } else if (idx < 6144){    // W2: 64 x 64
      int j = idx - 2048;
      Wt2[j] = (uint16_t)f2b(W2[j]);
    } else {                   // W3: 32 x 64
      int j = idx - 6144;
      Wt3[j] = (uint16_t)f2b(W3[j]);
    }
  }
}

// ---------- build h0 (tiled layout): [N] blocks of 32 rows x 32 k bf16 ----------
__global__ __launch_bounds__(256) void k_build_h0(const float* __restrict__ x, const int* __restrict__ tidx,
                                                  const float* __restrict__ emb, uint32_t* __restrict__ h0){
  int n = blockIdx.x*8 + (threadIdx.x>>5);
  int b = threadIdx.x & 31;
  const float* xr = x + ((size_t)b*NT + n)*14;
  const float* er = emb + (size_t)tidx[n]*8;
  float v[32];
  #pragma unroll
  for (int i=0;i<14;i++) v[i]=xr[i];
  #pragma unroll
  for (int i=0;i<8;i++) v[14+i]=er[i];
  #pragma unroll
  for (int i=22;i<32;i++) v[i]=0.f;
  uint32_t* dst = h0 + (size_t)n*512;   // 16*CIN u32, CIN=32
  const int base = (b>>4)*256 + (b&15)*8;
  #pragma unroll
  for (int u=0;u<16;u++)
    dst[base + (u>>3)*128 + (u&7)] = f2b(v[2*u]) | (f2b(v[2*u+1])<<16);
}

// ---------- gather helpers ----------
template<int STR>   // STR = u32 per node block = 16*CIN
__device__ __forceinline__ const uint32_t* nb(const uint32_t* __restrict__ hin,
                                              const uint32_t* __restrict__ zp, int c){
  return (c < NT) ? (hin + (size_t)c*STR) : zp;   // scalar select (c wave-uniform)
}
template<int KS>
__device__ __forceinline__ void gloadv(uint4 (&v)[KS], const uint32_t* __restrict__ p,
                                       const uint32_t (&off)[KS]){
  #pragma unroll
  for (int ks=0; ks<KS; ks++) v[ks] = *reinterpret_cast<const uint4*>(p + off[ks]);
}
template<int KS>
__device__ __forceinline__ void accum(float (&acc)[KS][8], const uint4 (&v)[KS]){
  #pragma unroll
  for (int ks=0;ks<KS;ks++){
    acc[ks][0]+=bf_lo(v[ks].x); acc[ks][1]+=bf_hi(v[ks].x);
    acc[ks][2]+=bf_lo(v[ks].y); acc[ks][3]+=bf_hi(v[ks].y);
    acc[ks][4]+=bf_lo(v[ks].z); acc[ks][5]+=bf_hi(v[ks].z);
    acc[ks][6]+=bf_lo(v[ks].w); acc[ks][7]+=bf_hi(v[ks].w);
  }
}

// ---------- fused layer: 2 waves per node (batch-rows 0-15 / 16-31); no LDS, no barriers;
// branch-free depth-4 edge pipeline over padded CSR; zero-page absorbs pads/overrun prefetch.
// Tiled block layout -> each wave gather is KS x 1KB contiguous; each store 512B contiguous.
// D = W * s^T via mfma_f32_16x16x32_bf16; D col(lane&15)=batch row, row((lane>>4)*4+reg)=out ch.
template<int CIN, int COUT, bool FINAL, int MINW>
__global__ __launch_bounds__(256, MINW) void k_layer(
    const uint32_t* __restrict__ hin,   // [NT] tiled blocks, CIN wide
    uint32_t* __restrict__ hout,        // [NT] tiled blocks, COUT wide (unused if FINAL)
    const int* __restrict__ rp, const int* __restrict__ cur,
    const uint16_t* __restrict__ cols, const uint32_t* __restrict__ zp,
    const uint16_t* __restrict__ Wt,    // [COUT][CIN] bf16 row-major
    const float* __restrict__ bias,
    const float* __restrict__ Wo, const float* __restrict__ bo,
    float* __restrict__ out)            // FINAL: tmp [NT][32] f32
{
  constexpr int KS  = CIN/32;
  constexpr int OT  = COUT/16;
  constexpr int STR = 16*CIN;

  const int t    = threadIdx.x;
  const int lane = t & 63;
  const int w    = t >> 6;
  const int l15  = lane & 15;
  const int lg   = lane >> 4;
  const int rt   = w & 1;
  const int node = blockIdx.x*2 + (w>>1);

  // tiled per-lane gather offsets (u32): lane needs s[rt*16+l15][lg*8+ks*32 .. +7]
  uint32_t off[KS];
  #pragma unroll
  for (int ks=0;ks<KS;ks++)
    off[ks] = (uint32_t)(rt*(CIN*8) + (ks*2 + (lg>>1))*128 + l15*8 + (lg&1)*4);

  const int e0 = __builtin_amdgcn_readfirstlane(rp[node]);
  const int e1 = __builtin_amdgcn_readfirstlane(rp[node+1]);
  const int dg = __builtin_amdgcn_readfirstlane(cur[node]) - e0;

  // prologue: first 4 targets + own block, all in flight together
  uint2 cc0 = *reinterpret_cast<const uint2*>(cols + e0);
  int q0 = __builtin_amdgcn_readfirstlane(cc0.x);
  int q1 = __builtin_amdgcn_readfirstlane(cc0.y);
  uint4 v0[KS], v1[KS], v2[KS], v3[KS], own[KS];
  gloadv<KS>(v0, nb<STR>(hin, zp, q0 & 0xffff), off);
  gloadv<KS>(v1, nb<STR>(hin, zp, (q0 >> 16) & 0xffff), off);
  gloadv<KS>(v2, nb<STR>(hin, zp, q1 & 0xffff), off);
  gloadv<KS>(v3, nb<STR>(hin, zp, (q1 >> 16) & 0xffff), off);
  gloadv<KS>(own, hin + (size_t)node*STR, off);
  uint2 ccA = *reinterpret_cast<const uint2*>(cols + e0 + 4);

  const float degf = (float)(dg > 1 ? dg : 1);
  float acc[KS][8];
  #pragma unroll
  for (int ks=0;ks<KS;ks++){
    acc[ks][0]=bf_lo(own[ks].x)*degf; acc[ks][1]=bf_hi(own[ks].x)*degf;
    acc[ks][2]=bf_lo(own[ks].y)*degf; acc[ks][3]=bf_hi(own[ks].y)*degf;
    acc[ks][4]=bf_lo(own[ks].z)*degf; acc[ks][5]=bf_hi(own[ks].z)*degf;
    acc[ks][6]=bf_lo(own[ks].w)*degf; acc[ks][7]=bf_hi(own[ks].w)*degf;
  }

  // branch-free depth-4 pipeline; trailing prefetches clamp to zero-page (L1-hot)
  for (int e = e0; e < e1; e += 4){
    uint2 ccN = *reinterpret_cast<const uint2*>(cols + e + 8);   // 8 sentinels at array end
    int p0 = __builtin_amdgcn_readfirstlane(ccA.x);
    int p1 = __builtin_amdgcn_readfirstlane(ccA.y);
    int n0 = (e+4 < e1) ? (p0 & 0xffff)         : NT;
    int n1 = (e+5 < e1) ? ((p0 >> 16) & 0xffff) : NT;
    int n2 = (e+6 < e1) ? (p1 & 0xffff)         : NT;
    int n3 = (e+7 < e1) ? ((p1 >> 16) & 0xffff) : NT;
    accum<KS>(acc, v0); gloadv<KS>(v0, nb<STR>(hin, zp, n0), off);
    accum<KS>(acc, v1); gloadv<KS>(v1, nb<STR>(hin, zp, n1), off);
    accum<KS>(acc, v2); gloadv<KS>(v2, nb<STR>(hin, zp, n2), off);
    accum<KS>(acc, v3); gloadv<KS>(v3, nb<STR>(hin, zp, n3), off);
    ccA = ccN;
  }

  // s = acc/deg -> bf16 B-frag (this wave's 16 batch rows)
  const float di = 1.0f / degf;
  short8 bfrag[KS];
  #pragma unroll
  for (int ks=0;ks<KS;ks++){
    short8 bf;
    #pragma unroll
    for (int j=0;j<8;j++) bf[j] = (short)f2b(acc[ks][j]*di);
    bfrag[ks]=bf;
  }

  if constexpr (!FINAL){
    #pragma unroll
    for (int ot=0;ot<OT;ot++){
      const int o0 = ot*16;
      short8 af[KS];
      #pragma unroll
      for (int ks=0;ks<KS;ks++)
        af[ks] = *reinterpret_cast<const short8*>(Wt + (o0 + l15)*CIN + ks*32 + lg*8);
      f32x4 d = *reinterpret_cast<const f32x4*>(bias + o0 + lg*4);   // bias folded into C
      #pragma unroll
      for (int ks=0;ks<KS;ks++)
        d = __builtin_amdgcn_mfma_f32_16x16x32_bf16(af[ks], bfrag[ks], d, 0,0,0);
      float a0=fmaxf(d[0],0.f), a1=fmaxf(d[1],0.f), a2=fmaxf(d[2],0.f), a3=fmaxf(d[3],0.f);
      uint2 p; p.x = f2b(a0) | (f2b(a1)<<16); p.y = f2b(a2) | (f2b(a3)<<16);
      // tiled store: lane (l15,lg) holds (brow=rt*16+l15, k=o0+lg*4..+3) -> 512B/wave contiguous
      *reinterpret_cast<uint2*>(hout + (size_t)node*(16*COUT)
                                + rt*(COUT*8) + ot*128 + l15*8 + lg*2) = p;
    }
  } else {
    float z = 0.f;
    #pragma unroll
    for (int ot=0;ot<OT;ot++){
      const int o0 = ot*16;
      short8 af[KS];
      #pragma unroll
      for (int ks=0;ks<KS;ks++)
        af[ks] = *reinterpret_cast<const short8*>(Wt + (o0 + l15)*CIN + ks*32 + lg*8);
      f32x4 d = *reinterpret_cast<const f32x4*>(bias + o0 + lg*4);
      #pragma unroll
      for (int ks=0;ks<KS;ks++)
        d = __builtin_amdgcn_mfma_f32_16x16x32_bf16(af[ks], bfrag[ks], d, 0,0,0);
      f32x4 wv = *reinterpret_cast<const f32x4*>(Wo + o0 + lg*4);
      #pragma unroll
      for (int j=0;j<4;j++) z += fmaxf(d[j],0.f)*wv[j];
    }
    z += __shfl_xor(z, 16, 64);
    z += __shfl_xor(z, 32, 64);
    if (lg == 0){
      float sg = 1.f/(1.f + expf(-(z + bo[0])));
      out[(size_t)node*32 + rt*16 + l15] = sg;   // contiguous 64B per wave; transposed later
    }
  }
}

// ---------- transpose tmp [NT][32] -> out [32][NT] (coalesced writes) ----------
__global__ __launch_bounds__(256) void k_tr(const float* __restrict__ tmp, float* __restrict__ out){
  int n = blockIdx.x*256 + threadIdx.x;
  if (n < NT){
    #pragma unroll
    for (int b=0;b<32;b++)
      out[(size_t)b*NT + n] = tmp[(size_t)n*32 + b];
  }
}

// ---------- workspace layout (bytes); total <= 213,772,512 (proven available round 5) ----------
static constexpr size_t OFF_BUFB = 106496000;                 // bufA: [NT] 4KB blocks max
static constexpr size_t OFF_ZP   = 212992000;                 // 4 KB zero page
static constexpr size_t OFF_WT1  = OFF_ZP  + 4096;
static constexpr size_t OFF_WT2  = OFF_WT1 + 4096;
static constexpr size_t OFF_WT3  = OFF_WT2 + 8192;
static constexpr size_t OFF_DEG  = OFF_WT3 + 4096;
static constexpr size_t OFF_RP   = OFF_DEG + 104000;
static constexpr size_t OFF_CUR  = OFF_RP  + 104016;
static constexpr size_t OFF_COLS = OFF_CUR + 104000;
static constexpr size_t WS_NEED  = OFF_COLS + 448016;         // 224008 u16 cols (incl 8 sentinels)

extern "C" void kernel_launch(void* const* d_in, const int* in_sizes, int n_in,
                              void* d_out, int out_size, void* d_ws, size_t ws_size,
                              hipStream_t stream)
{
  const float* x    = (const float*)d_in[0];
  const int*   ei   = (const int*)  d_in[1];
  const int*   tidx = (const int*)  d_in[2];
  const float* emb  = (const float*)d_in[3];
  const float* W1   = (const float*)d_in[4];
  const float* b1   = (const float*)d_in[5];
  const float* W2   = (const float*)d_in[6];
  const float* b2   = (const float*)d_in[7];
  const float* W3   = (const float*)d_in[8];
  const float* b3   = (const float*)d_in[9];
  const float* Wo   = (const float*)d_in[10];
  const float* bo   = (const float*)d_in[11];
  float* out = (float*)d_out;

  if (ws_size < WS_NEED) return;

  char* ws = (char*)d_ws;
  uint32_t* bufA  = (uint32_t*)(ws);
  uint32_t* bufB  = (uint32_t*)(ws + OFF_BUFB);
  uint32_t* zp    = (uint32_t*)(ws + OFF_ZP);
  uint16_t* Wt1   = (uint16_t*)(ws + OFF_WT1);
  uint16_t* Wt2   = (uint16_t*)(ws + OFF_WT2);
  uint16_t* Wt3   = (uint16_t*)(ws + OFF_WT3);
  int*      deg   = (int*)     (ws + OFF_DEG);
  int*      rp    = (int*)     (ws + OFF_RP);
  int*      cur   = (int*)     (ws + OFF_CUR);
  uint16_t* cols  = (uint16_t*)(ws + OFF_COLS);
  float*    tmpf  = (float*)   (ws + OFF_BUFB);   // bufB is free during FINAL layer

  k_zero_deg<<<(NT+255)/256, 256, 0, stream>>>(deg);
  k_count   <<<(NE+255)/256, 256, 0, stream>>>(ei, deg);
  k_scan    <<<1, 1024, 0, stream>>>(deg, rp, cur);
  k_init    <<<442, 256, 0, stream>>>(zp, (uint32_t*)cols);
  k_fill    <<<(NE+255)/256, 256, 0, stream>>>(ei, cur, cols);
  k_prepw   <<<1, 256, 0, stream>>>(W1, W2, W3, Wt1, Wt2, Wt3);

  for (int ch = 0; ch < 2; ch++){
    k_build_h0<<<NT/8, 256, 0, stream>>>(x + (size_t)ch*32*NT*14, tidx, emb, bufA);
    k_layer<32,64,false,8><<<NT/2, 256, 0, stream>>>(bufA, bufB, rp, cur, cols, zp, Wt1, b1,
                                                     nullptr, nullptr, nullptr);
    k_layer<64,64,false,7><<<NT/2, 256, 0, stream>>>(bufB, bufA, rp, cur, cols, zp, Wt2, b2,
                                                     nullptr, nullptr, nullptr);
    k_layer<64,32,true ,7><<<NT/2, 256, 0, stream>>>(bufA, nullptr, rp, cur, cols, zp, Wt3, b3,
                                                     Wo, bo, tmpf);
    k_tr<<<(NT+255)/256, 256, 0, stream>>>(tmpf, out + (size_t)ch*32*NT);
  }
}